// Round 1
// baseline (150.946 us; speedup 1.0000x reference)
//
#include <hip/hip_runtime.h>
#include <hip/hip_bf16.h>
#include <float.h>

// Problem constants (B, N, M from the reference)
#define B_      8
#define N_      8192
#define M_      8192
#define THREADS 256
#define P       8                    // a-points per thread (ILP)
#define SPLIT   8                    // M-loop split factor (parallelism)
#define CHUNK   (M_ / SPLIT)         // 1024 b-points per block
#define APB     (THREADS * P)        // 2048 a-points per block
#define ATILES  (N_ / APB)           // 4 a-tiles per (batch, dir)
#define NBLOCKS (2 * SPLIT * ATILES * B_)  // 512

// Pack xyz [n,3] -> float4 (x, y, z, x^2+y^2+z^2)
__global__ void pack_kernel(const float* __restrict__ xyz,
                            float4* __restrict__ out, int n) {
    int i = blockIdx.x * blockDim.x + threadIdx.x;
    if (i < n) {
        float x = xyz[3 * i + 0];
        float y = xyz[3 * i + 1];
        float z = xyz[3 * i + 2];
        out[i] = make_float4(x, y, z, fmaf(x, x, fmaf(y, y, z * z)));
    }
}

// Init output to FLT_MAX (atomicMin target); re-run every call (graph-safe)
__global__ void init_kernel(float* __restrict__ out, int n) {
    int i = blockIdx.x * blockDim.x + threadIdx.x;
    if (i < n) out[i] = FLT_MAX;
}

// Main kernel, packed-ws variant. Both directions fused in one grid.
__global__ __launch_bounds__(THREADS) void chamfer_ws(
    const float4* __restrict__ pk1,   // packed xyz1 [B*N]
    const float4* __restrict__ pk2,   // packed xyz2 [B*M]
    float* __restrict__ out)          // [B*N] dist1 then [B*M] dist2
{
    int bid = blockIdx.x;
    int dir   = bid & 1;              bid >>= 1;
    int chunk = bid & (SPLIT - 1);    bid >>= 3;   // log2(SPLIT)=3
    int atile = bid & (ATILES - 1);   bid >>= 2;   // log2(ATILES)=2
    int batch = bid;                                // 0..B_-1

    const float4* A  = dir ? pk2 : pk1;
    const float4* Bp = dir ? pk1 : pk2;
    float* o = out + (dir ? (B_ * N_) : 0);

    const int a0 = batch * N_ + atile * APB + threadIdx.x;

    float ax2[P], ay2[P], az2[P], aw[P], m[P];
#pragma unroll
    for (int p = 0; p < P; ++p) {
        float4 a = A[a0 + p * THREADS];   // coalesced: lane-consecutive float4
        ax2[p] = -2.0f * a.x;
        ay2[p] = -2.0f * a.y;
        az2[p] = -2.0f * a.z;
        aw[p]  = a.w;
        m[p]   = FLT_MAX;
    }

    // b-points: wave-uniform address -> scalar loads, no LDS needed
    const float4* bp = Bp + batch * M_ + chunk * CHUNK;
#pragma unroll 2
    for (int j = 0; j < CHUNK; j += 2) {
        float4 b0 = bp[j];
        float4 b1 = bp[j + 1];
#pragma unroll
        for (int p = 0; p < P; ++p) {
            float t0 = fmaf(ax2[p], b0.x, b0.w);
            t0 = fmaf(ay2[p], b0.y, t0);
            t0 = fmaf(az2[p], b0.z, t0);
            float t1 = fmaf(ax2[p], b1.x, b1.w);
            t1 = fmaf(ay2[p], b1.y, t1);
            t1 = fmaf(az2[p], b1.z, t1);
            m[p] = fminf(m[p], fminf(t0, t1));   // hope: v_min3_f32
        }
    }

#pragma unroll
    for (int p = 0; p < P; ++p) {
        float d = fmaxf(aw[p] + m[p], 0.0f);     // clamp: keeps uint-min valid
        atomicMin((unsigned int*)(o + a0 + p * THREADS), __float_as_uint(d));
    }
}

// Fallback variant if ws is too small: read raw [.,3] coords, norms inline.
__global__ __launch_bounds__(THREADS) void chamfer_raw(
    const float* __restrict__ xyz1,
    const float* __restrict__ xyz2,
    float* __restrict__ out)
{
    int bid = blockIdx.x;
    int dir   = bid & 1;              bid >>= 1;
    int chunk = bid & (SPLIT - 1);    bid >>= 3;
    int atile = bid & (ATILES - 1);   bid >>= 2;
    int batch = bid;

    const float* A  = dir ? xyz2 : xyz1;
    const float* Bp = dir ? xyz1 : xyz2;
    float* o = out + (dir ? (B_ * N_) : 0);

    const int a0 = batch * N_ + atile * APB + threadIdx.x;

    float ax2[P], ay2[P], az2[P], aw[P], m[P];
#pragma unroll
    for (int p = 0; p < P; ++p) {
        int idx = a0 + p * THREADS;
        float x = A[3 * idx + 0];
        float y = A[3 * idx + 1];
        float z = A[3 * idx + 2];
        ax2[p] = -2.0f * x;
        ay2[p] = -2.0f * y;
        az2[p] = -2.0f * z;
        aw[p]  = fmaf(x, x, fmaf(y, y, z * z));
        m[p]   = FLT_MAX;
    }

    const float* bp = Bp + 3 * (batch * M_ + chunk * CHUNK);
#pragma unroll 2
    for (int j = 0; j < CHUNK; j += 2) {
        float b0x = bp[3 * j + 0], b0y = bp[3 * j + 1], b0z = bp[3 * j + 2];
        float b1x = bp[3 * j + 3], b1y = bp[3 * j + 4], b1z = bp[3 * j + 5];
        float b0w = fmaf(b0x, b0x, fmaf(b0y, b0y, b0z * b0z));
        float b1w = fmaf(b1x, b1x, fmaf(b1y, b1y, b1z * b1z));
#pragma unroll
        for (int p = 0; p < P; ++p) {
            float t0 = fmaf(ax2[p], b0x, b0w);
            t0 = fmaf(ay2[p], b0y, t0);
            t0 = fmaf(az2[p], b0z, t0);
            float t1 = fmaf(ax2[p], b1x, b1w);
            t1 = fmaf(ay2[p], b1y, t1);
            t1 = fmaf(az2[p], b1z, t1);
            m[p] = fminf(m[p], fminf(t0, t1));
        }
    }

#pragma unroll
    for (int p = 0; p < P; ++p) {
        float d = fmaxf(aw[p] + m[p], 0.0f);
        atomicMin((unsigned int*)(o + a0 + p * THREADS), __float_as_uint(d));
    }
}

extern "C" void kernel_launch(void* const* d_in, const int* in_sizes, int n_in,
                              void* d_out, int out_size, void* d_ws, size_t ws_size,
                              hipStream_t stream) {
    const float* xyz1 = (const float*)d_in[0];
    const float* xyz2 = (const float*)d_in[1];
    float* out = (float*)d_out;

    const int n_out = B_ * N_ + B_ * M_;   // 131072
    init_kernel<<<(n_out + 255) / 256, 256, 0, stream>>>(out, n_out);

    const size_t need = (size_t)(B_ * (N_ + M_)) * sizeof(float4);  // 2 MiB
    if (ws_size >= need) {
        float4* pk1 = (float4*)d_ws;        // [B*N]
        float4* pk2 = pk1 + (size_t)B_ * N_; // [B*M]
        pack_kernel<<<(B_ * N_ + 255) / 256, 256, 0, stream>>>(xyz1, pk1, B_ * N_);
        pack_kernel<<<(B_ * M_ + 255) / 256, 256, 0, stream>>>(xyz2, pk2, B_ * M_);
        chamfer_ws<<<NBLOCKS, THREADS, 0, stream>>>(pk1, pk2, out);
    } else {
        chamfer_raw<<<NBLOCKS, THREADS, 0, stream>>>(xyz1, xyz2, out);
    }
}

// Round 2
// 118.141 us; speedup vs baseline: 1.2777x; 1.2777x over previous
//
#include <hip/hip_runtime.h>
#include <hip/hip_bf16.h>
#include <float.h>

// Problem constants (B, N, M from the reference)
#define B_      8
#define N_      8192
#define M_      8192
#define THREADS 256
#define P       8                    // a-points per thread (ILP)
#define SPLIT   32                   // M-loop split factor (parallelism)
#define CHUNK   (M_ / SPLIT)         // 256 b-points per block
#define APB     (THREADS * P)        // 2048 a-points per block
#define ATILES  (N_ / APB)           // 4 a-tiles per (batch, dir)
#define NBLOCKS (2 * SPLIT * ATILES * B_)  // 2048

// Pack xyz [n,3] -> float4 (x, y, z, x^2+y^2+z^2)
__global__ void pack_kernel(const float* __restrict__ xyz,
                            float4* __restrict__ out, int n) {
    int i = blockIdx.x * blockDim.x + threadIdx.x;
    if (i < n) {
        float x = xyz[3 * i + 0];
        float y = xyz[3 * i + 1];
        float z = xyz[3 * i + 2];
        out[i] = make_float4(x, y, z, fmaf(x, x, fmaf(y, y, z * z)));
    }
}

// Init output to FLT_MAX (atomicMin target); re-run every call (graph-safe)
__global__ void init_kernel(float* __restrict__ out, int n) {
    int i = blockIdx.x * blockDim.x + threadIdx.x;
    if (i < n) out[i] = FLT_MAX;
}

// Main kernel, packed-ws variant. Both directions fused in one grid.
__global__ __launch_bounds__(THREADS) void chamfer_ws(
    const float4* __restrict__ pk1,   // packed xyz1 [B*N]
    const float4* __restrict__ pk2,   // packed xyz2 [B*M]
    float* __restrict__ out)          // [B*N] dist1 then [B*M] dist2
{
    int bid = blockIdx.x;
    int dir   = bid & 1;                 bid >>= 1;
    int chunk = bid & (SPLIT - 1);       bid /= SPLIT;    // pow2 -> shift
    int atile = bid & (ATILES - 1);      bid /= ATILES;
    int batch = bid;                                      // 0..B_-1

    const float4* A  = dir ? pk2 : pk1;
    const float4* Bp = dir ? pk1 : pk2;
    float* o = out + (dir ? (B_ * N_) : 0);

    const int a0 = batch * N_ + atile * APB + threadIdx.x;

    float ax2[P], ay2[P], az2[P], aw[P], m[P];
#pragma unroll
    for (int p = 0; p < P; ++p) {
        float4 a = A[a0 + p * THREADS];   // coalesced: lane-consecutive float4
        ax2[p] = -2.0f * a.x;
        ay2[p] = -2.0f * a.y;
        az2[p] = -2.0f * a.z;
        aw[p]  = a.w;
        m[p]   = FLT_MAX;
    }

    // b-points: wave-uniform address -> broadcast via L1; chunk is 4 KB
    const float4* bp = Bp + batch * M_ + chunk * CHUNK;
#pragma unroll 2
    for (int j = 0; j < CHUNK; j += 2) {
        float4 b0 = bp[j];
        float4 b1 = bp[j + 1];
#pragma unroll
        for (int p = 0; p < P; ++p) {
            float t0 = fmaf(ax2[p], b0.x, b0.w);
            t0 = fmaf(ay2[p], b0.y, t0);
            t0 = fmaf(az2[p], b0.z, t0);
            float t1 = fmaf(ax2[p], b1.x, b1.w);
            t1 = fmaf(ay2[p], b1.y, t1);
            t1 = fmaf(az2[p], b1.z, t1);
            m[p] = fminf(m[p], fminf(t0, t1));   // fuses to v_min3_f32
        }
    }

#pragma unroll
    for (int p = 0; p < P; ++p) {
        float d = fmaxf(aw[p] + m[p], 0.0f);     // clamp: keeps uint-min valid
        atomicMin((unsigned int*)(o + a0 + p * THREADS), __float_as_uint(d));
    }
}

// Fallback variant if ws is too small: read raw [.,3] coords, norms inline.
__global__ __launch_bounds__(THREADS) void chamfer_raw(
    const float* __restrict__ xyz1,
    const float* __restrict__ xyz2,
    float* __restrict__ out)
{
    int bid = blockIdx.x;
    int dir   = bid & 1;                 bid >>= 1;
    int chunk = bid & (SPLIT - 1);       bid /= SPLIT;
    int atile = bid & (ATILES - 1);      bid /= ATILES;
    int batch = bid;

    const float* A  = dir ? xyz2 : xyz1;
    const float* Bp = dir ? xyz1 : xyz2;
    float* o = out + (dir ? (B_ * N_) : 0);

    const int a0 = batch * N_ + atile * APB + threadIdx.x;

    float ax2[P], ay2[P], az2[P], aw[P], m[P];
#pragma unroll
    for (int p = 0; p < P; ++p) {
        int idx = a0 + p * THREADS;
        float x = A[3 * idx + 0];
        float y = A[3 * idx + 1];
        float z = A[3 * idx + 2];
        ax2[p] = -2.0f * x;
        ay2[p] = -2.0f * y;
        az2[p] = -2.0f * z;
        aw[p]  = fmaf(x, x, fmaf(y, y, z * z));
        m[p]   = FLT_MAX;
    }

    const float* bp = Bp + 3 * (batch * M_ + chunk * CHUNK);
#pragma unroll 2
    for (int j = 0; j < CHUNK; j += 2) {
        float b0x = bp[3 * j + 0], b0y = bp[3 * j + 1], b0z = bp[3 * j + 2];
        float b1x = bp[3 * j + 3], b1y = bp[3 * j + 4], b1z = bp[3 * j + 5];
        float b0w = fmaf(b0x, b0x, fmaf(b0y, b0y, b0z * b0z));
        float b1w = fmaf(b1x, b1x, fmaf(b1y, b1y, b1z * b1z));
#pragma unroll
        for (int p = 0; p < P; ++p) {
            float t0 = fmaf(ax2[p], b0x, b0w);
            t0 = fmaf(ay2[p], b0y, t0);
            t0 = fmaf(az2[p], b0z, t0);
            float t1 = fmaf(ax2[p], b1x, b1w);
            t1 = fmaf(ay2[p], b1y, t1);
            t1 = fmaf(az2[p], b1z, t1);
            m[p] = fminf(m[p], fminf(t0, t1));
        }
    }

#pragma unroll
    for (int p = 0; p < P; ++p) {
        float d = fmaxf(aw[p] + m[p], 0.0f);
        atomicMin((unsigned int*)(o + a0 + p * THREADS), __float_as_uint(d));
    }
}

extern "C" void kernel_launch(void* const* d_in, const int* in_sizes, int n_in,
                              void* d_out, int out_size, void* d_ws, size_t ws_size,
                              hipStream_t stream) {
    const float* xyz1 = (const float*)d_in[0];
    const float* xyz2 = (const float*)d_in[1];
    float* out = (float*)d_out;

    const int n_out = B_ * N_ + B_ * M_;   // 131072
    init_kernel<<<(n_out + 255) / 256, 256, 0, stream>>>(out, n_out);

    const size_t need = (size_t)(B_ * (N_ + M_)) * sizeof(float4);  // 2 MiB
    if (ws_size >= need) {
        float4* pk1 = (float4*)d_ws;        // [B*N]
        float4* pk2 = pk1 + (size_t)B_ * N_; // [B*M]
        pack_kernel<<<(B_ * N_ + 255) / 256, 256, 0, stream>>>(xyz1, pk1, B_ * N_);
        pack_kernel<<<(B_ * M_ + 255) / 256, 256, 0, stream>>>(xyz2, pk2, B_ * M_);
        chamfer_ws<<<NBLOCKS, THREADS, 0, stream>>>(pk1, pk2, out);
    } else {
        chamfer_raw<<<NBLOCKS, THREADS, 0, stream>>>(xyz1, xyz2, out);
    }
}